// Round 19
// baseline (128.060 us; speedup 1.0000x reference)
//
#include <hip/hip_runtime.h>

// MHA forward: B=2 T=2048 C=1024 H=16 D=64, causal, scale 1/sqrt(C)=1/32
// cast -> QKV gemm (64x128 tile, 3-deep counted-vmcnt, chunk-swizzled LDS,
// 1536 blocks for occupancy) -> flash attn (1 q-tile/block, LDS dbuf K/V) ->
// out gemm (64x64 tile, same pipeline, 1024 blocks)

#define Bsz 2
#define Tsz 2048
#define Cdim 1024
#define Hn 16
#define Dh 64

typedef short bf16x8 __attribute__((ext_vector_type(8)));
typedef float f32x4 __attribute__((ext_vector_type(4)));
typedef unsigned short u16;

#define MFMA(a, b, c) __builtin_amdgcn_mfma_f32_16x16x32_bf16(a, b, c, 0, 0, 0)
#define NEGINF (-__builtin_inff())
#define EXP2(x) __builtin_amdgcn_exp2f(x)

#define GLD16(g, l)                                                            \
  __builtin_amdgcn_global_load_lds((const __attribute__((address_space(1))) void*)(g), \
                                   (__attribute__((address_space(3))) void*)(l), 16, 0, 0)

__device__ __forceinline__ u16 f2bf(float f) {
  unsigned u = __builtin_bit_cast(unsigned, f);
  unsigned r = 0x7fffu + ((u >> 16) & 1u);
  return (u16)((u + r) >> 16);
}

__device__ __forceinline__ unsigned cvtpk(float lo, float hi) {
  unsigned r;
  asm("v_cvt_pk_bf16_f32 %0, %1, %2" : "=v"(r) : "v"(lo), "v"(hi));
  return r;
}

// flat f32 -> bf16 cast, 4 elems/thread
__global__ __launch_bounds__(256) void k_cast_x(const float* __restrict__ x,
                                                u16* __restrict__ xb, int n4) {
  int i = blockIdx.x * 256 + threadIdx.x;
  if (i >= n4) return;
  float4 v = reinterpret_cast<const float4*>(x)[i];
  ushort4 o;
  o.x = f2bf(v.x); o.y = f2bf(v.y); o.z = f2bf(v.z); o.w = f2bf(v.w);
  reinterpret_cast<ushort4*>(xb)[i] = o;
}

// Wq/Wk/Wv [H][C][D] f32 -> wt [(m*H+h)*D+d][C] bf16 via LDS tile transpose.
__global__ __launch_bounds__(256) void k_cast_w(const float* __restrict__ Wq,
                                                const float* __restrict__ Wk,
                                                const float* __restrict__ Wv,
                                                u16* __restrict__ wt) {
  __shared__ u16 tile[64][68];
  const int mh = blockIdx.y;
  const int m = mh >> 4, h = mh & 15;
  const float* src = (m == 0 ? Wq : m == 1 ? Wk : Wv) + (size_t)h * Cdim * Dh;
  const int c0 = blockIdx.x * 64;
  const int tid = threadIdx.x;
  const int cc = tid >> 4, d4 = (tid & 15) * 4;
#pragma unroll
  for (int i = 0; i < 4; ++i) {
    int c = i * 16 + cc;
    float4 v = *(const float4*)(src + (size_t)(c0 + c) * Dh + d4);
    tile[d4 + 0][c] = f2bf(v.x);
    tile[d4 + 1][c] = f2bf(v.y);
    tile[d4 + 2][c] = f2bf(v.z);
    tile[d4 + 3][c] = f2bf(v.w);
  }
  __syncthreads();
  const int c4 = (tid & 15) * 4, dd = tid >> 4;
#pragma unroll
  for (int i = 0; i < 4; ++i) {
    int d = i * 16 + dd;
    ushort4 o;
    o.x = tile[d][c4]; o.y = tile[d][c4 + 1];
    o.z = tile[d][c4 + 2]; o.w = tile[d][c4 + 3];
    *(ushort4*)(wt + (size_t)(mh * 64 + d) * Cdim + c0 + c4) = o;
  }
}

// QKV GEMM: 64x128 tile, BK=32, 3-deep counted-vmcnt pipeline, chunk-swizzled
// LDS. Grid (24,64) = 1536 blocks (4 resident/CU at 36KB LDS).
__global__ __launch_bounds__(256) void k_gemm_qkv(const u16* __restrict__ xb,
                                                  const u16* __restrict__ wt,
                                                  u16* __restrict__ qb,
                                                  u16* __restrict__ kb,
                                                  u16* __restrict__ vtb) {
  __shared__ __align__(16) u16 As[3][2048], Bs[3][4096];
  const int tid = threadIdx.x, lane = tid & 63, wid = tid >> 6;
  const int cl = lane & 15, kg = lane >> 4;
  const int row0 = blockIdx.y * 64, col0 = blockIdx.x * 128;
  const int wrow = (wid >> 1) * 32, wcol = (wid & 1) * 64;
  f32x4 acc[2][4] = {};
  // wave-uniform LDS base + lane*16B; global source chunk inverse-swizzled
  const int csrc = ((lane & 3) ^ ((lane >> 3) & 3)) * 8;
  const int srow = wid * 16 + (lane >> 2);
  const u16* a_src = xb + (size_t)(row0 + srow) * Cdim + csrc;
  const u16* b_src0 = wt + (size_t)(col0 + srow) * Cdim + csrc;
  const u16* b_src1 = wt + (size_t)(col0 + 64 + srow) * Cdim + csrc;

  auto stage = [&](int buf, int ke) {
    GLD16(a_src + ke, &As[buf][512 * wid]);
    GLD16(b_src0 + ke, &Bs[buf][512 * wid]);
    GLD16(b_src1 + ke, &Bs[buf][2048 + 512 * wid]);
  };

  const int rdswz = (kg ^ ((cl >> 1) & 3)) * 8;

  stage(0, 0);
  stage(1, 32);
  stage(2, 64);
  for (int kk = 0; kk < 32; ++kk) {
    if (kk < 30)
      asm volatile("s_waitcnt vmcnt(6)" ::: "memory");
    else if (kk == 30)
      asm volatile("s_waitcnt vmcnt(3)" ::: "memory");
    else
      asm volatile("s_waitcnt vmcnt(0)" ::: "memory");
    __builtin_amdgcn_s_barrier();  // all waves: buf[kk%3] ready
    const int cur = kk % 3;
    bf16x8 af[2], bfr[4];
#pragma unroll
    for (int mi = 0; mi < 2; ++mi)
      af[mi] = *(const bf16x8*)&As[cur][(wrow + mi * 16 + cl) * 32 + rdswz];
#pragma unroll
    for (int ni = 0; ni < 4; ++ni)
      bfr[ni] = *(const bf16x8*)&Bs[cur][(wcol + ni * 16 + cl) * 32 + rdswz];
#pragma unroll
    for (int mi = 0; mi < 2; ++mi)
#pragma unroll
      for (int ni = 0; ni < 4; ++ni)
        acc[mi][ni] = MFMA(af[mi], bfr[ni], acc[mi][ni]);
    __builtin_amdgcn_s_barrier();  // all waves done reading buf[kk%3]
    if (kk + 3 < 32) stage(cur, (kk + 3) * 32);
  }
#pragma unroll
  for (int mi = 0; mi < 2; ++mi) {
#pragma unroll
    for (int ni = 0; ni < 4; ++ni) {
      int n = col0 + wcol + ni * 16 + cl;
      int m = n >> 10, h = (n >> 6) & 15, d = n & 63;
#pragma unroll
      for (int j2 = 0; j2 < 4; ++j2) {
        int r = row0 + wrow + mi * 16 + kg * 4 + j2;
        int b = r >> 11, t = r & 2047;
        float av = acc[mi][ni][j2];
        if (m == 0) av *= 0.04508422f;  // 1/sqrt(C) * log2(e)
        u16 v = f2bf(av);
        size_t bh = (size_t)(b * Hn + h);
        if (m == 0)
          qb[(bh * Tsz + t) * Dh + d] = v;
        else if (m == 1)
          kb[(bh * Tsz + t) * Dh + d] = v;
        else
          vtb[(bh * Dh + d) * Tsz + t] = v;
      }
    }
  }
}

// ---- flash attention: 1024 blocks, 1 q-tile/block, LDS-staged dbuf K/V ----
// Grid 1024: xcd = bid&7; s = bid>>3; t = 31-(s>>2) (longest first);
// bh p = xcd + 8*(s&3). All blocks of one (b,h) share an XCD. 4 waves/block,
// wave wid owns q-rows [t*64+wid*16,+16). LDS 40KB -> 4 blocks/CU.
__global__ __launch_bounds__(256, 4) void k_attn(const u16* __restrict__ qb,
                                                 const u16* __restrict__ kb,
                                                 const u16* __restrict__ vtb,
                                                 u16* __restrict__ ob) {
  __shared__ __align__(16) u16 KV[2][8192];   // [buf][ K: 0..4095 | V: 4096..8191 ]
  __shared__ __align__(16) u16 Plds[4][1024]; // per-wave P roundtrip
  const int lane = threadIdx.x & 63, wid = threadIdx.x >> 6;
  const int cl = lane & 15, kg = lane >> 4;
  const int s = blockIdx.x >> 3;
  const int t = 31 - (s >> 2);
  const int p = (blockIdx.x & 7) + 8 * (s & 3);
  const int h = p & 15, b = p >> 4;
  const int qr = t * 64 + wid * 16;
  const size_t bh = (size_t)(b * Hn + h);
  const u16* Qp = qb + bh * Tsz * Dh;
  const u16* Kp = kb + bh * Tsz * Dh;
  const u16* Vp = vtb + bh * Dh * Tsz;

  const u16* pk_src[2];
  const u16* pv_src[2];
#pragma unroll
  for (int c = 0; c < 2; ++c) {
    int lo = c * 4096 + wid * 1024 + lane * 16;
    int r = lo >> 7, cb = lo & 127;
    int cbs = cb ^ ((r & 7) << 4);
    pk_src[c] = Kp + r * Dh + (cbs >> 1);
    pv_src[c] = Vp + (size_t)r * Tsz + (cbs >> 1);
  }

  auto stage = [&](int buf, int kt) {
    GLD16(pk_src[0] + kt * 4096, &KV[buf][(wid * 1024) >> 1]);
    GLD16(pk_src[1] + kt * 4096, &KV[buf][(4096 + wid * 1024) >> 1]);
    GLD16(pv_src[0] + kt * 64, &KV[buf][(8192 + wid * 1024) >> 1]);
    GLD16(pv_src[1] + kt * 64, &KV[buf][(12288 + wid * 1024) >> 1]);
  };

  bf16x8 qa0 = *(const bf16x8*)(Qp + (size_t)(qr + cl) * Dh + kg * 8);
  bf16x8 qa1 = *(const bf16x8*)(Qp + (size_t)(qr + cl) * Dh + 32 + kg * 8);

  f32x4 o[4] = {};
  float m = NEGINF, l = 0.f;

  char* pb = (char*)&Plds[wid][0];
  const int rdoff0 = ((cl << 7) + (kg << 4)) ^ ((cl & 7) << 4);
  const int rdoff1 = ((cl << 7) + 64 + (kg << 4)) ^ ((cl & 7) << 4);
  const int rowoff = wid * 16;
  const int swz0 = (kg * 16) ^ ((cl & 7) << 4);
  const int swz1 = (kg * 16 + 64) ^ ((cl & 7) << 4);

  stage(0, 0);
  __syncthreads();
  int cur = 0;
  for (int kt = 0; kt <= t; ++kt) {
    if (kt < t) stage(cur ^ 1, kt + 1);
    char* kvb = (char*)&KV[cur][0];
    // K frags from LDS
    bf16x8 ka[8];
#pragma unroll
    for (int nt = 0; nt < 4; ++nt) {
      int rbase = (nt * 16 + cl) << 7;
      ka[nt * 2] = *(const bf16x8*)(kvb + rbase + swz0);
      ka[nt * 2 + 1] = *(const bf16x8*)(kvb + rbase + swz1);
    }
    f32x4 sv[4];
    __builtin_amdgcn_s_setprio(1);
#pragma unroll
    for (int nt = 0; nt < 4; ++nt) {
      f32x4 z = {};
      z = MFMA(ka[nt * 2], qa0, z);
      z = MFMA(ka[nt * 2 + 1], qa1, z);
      sv[nt] = z;
    }
    __builtin_amdgcn_s_setprio(0);
    // V frags from LDS
    bf16x8 vf[8];
#pragma unroll
    for (int dt = 0; dt < 4; ++dt) {
      int rbase = 8192 + ((dt * 16 + cl) << 7);
      vf[dt * 2] = *(const bf16x8*)(kvb + rbase + swz0);
      vf[dt * 2 + 1] = *(const bf16x8*)(kvb + rbase + swz1);
    }
    if (kt == t) {  // diag tile mask
#pragma unroll
      for (int nt = 0; nt < 4; ++nt)
#pragma unroll
        for (int j = 0; j < 4; ++j)
          if (nt * 16 + kg * 4 + j > rowoff + cl) sv[nt][j] = NEGINF;
    }
    float tm = fmaxf(fmaxf(fmaxf(sv[0][0], sv[0][1]), fmaxf(sv[0][2], sv[0][3])),
                     fmaxf(fmaxf(sv[1][0], sv[1][1]), fmaxf(sv[1][2], sv[1][3])));
    tm = fmaxf(tm, fmaxf(fmaxf(fmaxf(sv[2][0], sv[2][1]), fmaxf(sv[2][2], sv[2][3])),
                         fmaxf(fmaxf(sv[3][0], sv[3][1]), fmaxf(sv[3][2], sv[3][3]))));
    if (!__all(tm <= m + 8.0f)) {
      tm = fmaxf(tm, __shfl_xor(tm, 16));
      tm = fmaxf(tm, __shfl_xor(tm, 32));
      float mnew = fmaxf(m, tm);
      float corr = EXP2(m - mnew);
      m = mnew;
      l *= corr;
      float c0 = __shfl(corr, kg * 4 + 0);
      float c1 = __shfl(corr, kg * 4 + 1);
      float c2 = __shfl(corr, kg * 4 + 2);
      float c3 = __shfl(corr, kg * 4 + 3);
#pragma unroll
      for (int dt = 0; dt < 4; ++dt) {
        o[dt][0] *= c0; o[dt][1] *= c1; o[dt][2] *= c2; o[dt][3] *= c3;
      }
    }
    float rs = 0.f;
#pragma unroll
    for (int nt = 0; nt < 4; ++nt)
#pragma unroll
      for (int j = 0; j < 4; ++j) {
        float pv = EXP2(sv[nt][j] - m);
        sv[nt][j] = pv;
        rs += pv;
      }
    l += rs;
#pragma unroll
    for (int nt = 0; nt < 4; ++nt) {
      uint2 pk;
      pk.x = cvtpk(sv[nt][0], sv[nt][1]);
      pk.y = cvtpk(sv[nt][2], sv[nt][3]);
      int waddr = ((cl << 7) + (nt << 5) + (kg << 3)) ^ ((cl & 7) << 4);
      *(uint2*)(pb + waddr) = pk;
    }
    bf16x8 pa0 = *(const bf16x8*)(pb + rdoff0);
    bf16x8 pa1 = *(const bf16x8*)(pb + rdoff1);
    __builtin_amdgcn_s_setprio(1);
#pragma unroll
    for (int dt = 0; dt < 4; ++dt) {
      o[dt] = MFMA(pa0, vf[dt * 2], o[dt]);
      o[dt] = MFMA(pa1, vf[dt * 2 + 1], o[dt]);
    }
    __builtin_amdgcn_s_setprio(0);
    __syncthreads();  // drains next-tile gld_lds + protects buffer reuse
    cur ^= 1;
  }

  // epilogue: finish lazy l reduction, broadcast 1/l per O row
  l += __shfl_xor(l, 16);
  l += __shfl_xor(l, 32);
  float i0 = 1.f / __shfl(l, kg * 4 + 0), i1 = 1.f / __shfl(l, kg * 4 + 1);
  float i2 = 1.f / __shfl(l, kg * 4 + 2), i3 = 1.f / __shfl(l, kg * 4 + 3);
  float inv[4] = {i0, i1, i2, i3};
#pragma unroll
  for (int dt = 0; dt < 4; ++dt)
#pragma unroll
    for (int j = 0; j < 4; ++j) {
      int tr = qr + kg * 4 + j;
      ob[(size_t)(b * Tsz + tr) * Cdim + h * Dh + dt * 16 + cl] = f2bf(o[dt][j] * inv[j]);
    }
}

// Out GEMM: 64x64 tile, BK=32, 3-deep counted-vmcnt pipeline. Grid (16,64) =
// 1024 blocks (4 resident/CU at 24KB LDS).
__global__ __launch_bounds__(256) void k_gemm_out(const u16* __restrict__ ob,
                                                  const u16* __restrict__ wob,
                                                  const float* __restrict__ bo,
                                                  float* __restrict__ out) {
  __shared__ __align__(16) u16 As[3][2048], Bs[3][2048];
  const int tid = threadIdx.x, lane = tid & 63, wid = tid >> 6;
  const int cl = lane & 15, kg = lane >> 4;
  const int row0 = blockIdx.y * 64, col0 = blockIdx.x * 64;
  const int wrow = (wid >> 1) * 32, wcol = (wid & 1) * 32;
  f32x4 acc[2][2] = {};
  const int csrc = ((lane & 3) ^ ((lane >> 3) & 3)) * 8;
  const int srow = wid * 16 + (lane >> 2);
  const u16* a_src = ob + (size_t)(row0 + srow) * Cdim + csrc;
  const u16* b_src = wob + (size_t)(col0 + srow) * Cdim + csrc;

  auto stage = [&](int buf, int ke) {
    GLD16(a_src + ke, &As[buf][512 * wid]);
    GLD16(b_src + ke, &Bs[buf][512 * wid]);
  };

  const int rdswz = (kg ^ ((cl >> 1) & 3)) * 8;

  stage(0, 0);
  stage(1, 32);
  stage(2, 64);
  for (int kk = 0; kk < 32; ++kk) {
    if (kk < 30)
      asm volatile("s_waitcnt vmcnt(4)" ::: "memory");
    else if (kk == 30)
      asm volatile("s_waitcnt vmcnt(2)" ::: "memory");
    else
      asm volatile("s_waitcnt vmcnt(0)" ::: "memory");
    __builtin_amdgcn_s_barrier();
    const int cur = kk % 3;
    bf16x8 af[2], bfr[2];
#pragma unroll
    for (int mi = 0; mi < 2; ++mi)
      af[mi] = *(const bf16x8*)&As[cur][(wrow + mi * 16 + cl) * 32 + rdswz];
#pragma unroll
    for (int ni = 0; ni < 2; ++ni)
      bfr[ni] = *(const bf16x8*)&Bs[cur][(wcol + ni * 16 + cl) * 32 + rdswz];
#pragma unroll
    for (int mi = 0; mi < 2; ++mi)
#pragma unroll
      for (int ni = 0; ni < 2; ++ni)
        acc[mi][ni] = MFMA(af[mi], bfr[ni], acc[mi][ni]);
    __builtin_amdgcn_s_barrier();
    if (kk + 3 < 32) stage(cur, (kk + 3) * 32);
  }
#pragma unroll
  for (int mi = 0; mi < 2; ++mi) {
#pragma unroll
    for (int ni = 0; ni < 2; ++ni) {
      int n = col0 + wcol + ni * 16 + cl;
      float bias = bo[n];
#pragma unroll
      for (int j2 = 0; j2 < 4; ++j2) {
        int r = row0 + wrow + mi * 16 + kg * 4 + j2;
        out[(size_t)r * Cdim + n] = acc[mi][ni][j2] + bias;
      }
    }
  }
}

extern "C" void kernel_launch(void* const* d_in, const int* in_sizes, int n_in,
                              void* d_out, int out_size, void* d_ws, size_t ws_size,
                              hipStream_t stream) {
  (void)in_sizes; (void)n_in; (void)out_size; (void)ws_size;
  const float* x = (const float*)d_in[0];
  const float* Wq = (const float*)d_in[1];
  const float* Wk = (const float*)d_in[2];
  const float* Wv = (const float*)d_in[3];
  const float* Wo = (const float*)d_in[4];
  const float* bo = (const float*)d_in[5];
  float* out = (float*)d_out;
  char* ws = (char*)d_ws;
  u16* xb = (u16*)(ws);                  // 8 MiB  x bf16 [4096][1024]
  u16* wt = (u16*)(ws + (8u << 20));     // 6 MiB  Wqkv^T bf16 [3072][1024]
  u16* wob = (u16*)(ws + (14u << 20));   // 2 MiB  Wo bf16 [1024][1024]
  u16* qb = (u16*)(ws + (16u << 20));    // 8 MiB  Q (pre-scaled)
  u16* kb = (u16*)(ws + (24u << 20));    // 8 MiB  K
  u16* vtb = (u16*)(ws + (32u << 20));   // 8 MiB  V^T
  u16* ob = (u16*)(ws + (40u << 20));    // 8 MiB  attn out bf16

  k_cast_x<<<4096, 256, 0, stream>>>(x, xb, Bsz * Tsz * Cdim / 4);
  k_cast_x<<<1024, 256, 0, stream>>>(Wo, wob, Cdim * Cdim / 4);
  k_cast_w<<<dim3(16, 48), 256, 0, stream>>>(Wq, Wk, Wv, wt);
  k_gemm_qkv<<<dim3(24, 64), 256, 0, stream>>>(xb, wt, qb, kb, vtb);
  k_attn<<<1024, 256, 0, stream>>>(qb, kb, vtb, ob);
  k_gemm_out<<<dim3(16, 64), 256, 0, stream>>>(ob, wob, bo, out);
}

// Round 20
// 111.332 us; speedup vs baseline: 1.1503x; 1.1503x over previous
//
#include <hip/hip_runtime.h>

// MHA forward: B=2 T=2048 C=1024 H=16 D=64, causal, scale 1/sqrt(C)=1/32
// cast -> QKV gemm (3-deep counted-vmcnt pipeline, chunk-swizzled LDS) ->
// flash attn (1024 blocks, 1 q-tile/block, LDS-staged dbuf K/V, swapped QK^T,
// exp2, defer-max, XCD clustering, longest-first) -> out gemm (same pipeline)
// [revert to round-18 best-known configuration: 112.2 us]

#define Bsz 2
#define Tsz 2048
#define Cdim 1024
#define Hn 16
#define Dh 64

typedef short bf16x8 __attribute__((ext_vector_type(8)));
typedef float f32x4 __attribute__((ext_vector_type(4)));
typedef unsigned short u16;

#define MFMA(a, b, c) __builtin_amdgcn_mfma_f32_16x16x32_bf16(a, b, c, 0, 0, 0)
#define NEGINF (-__builtin_inff())
#define EXP2(x) __builtin_amdgcn_exp2f(x)

#define GLD16(g, l)                                                            \
  __builtin_amdgcn_global_load_lds((const __attribute__((address_space(1))) void*)(g), \
                                   (__attribute__((address_space(3))) void*)(l), 16, 0, 0)

__device__ __forceinline__ u16 f2bf(float f) {
  unsigned u = __builtin_bit_cast(unsigned, f);
  unsigned r = 0x7fffu + ((u >> 16) & 1u);
  return (u16)((u + r) >> 16);
}

__device__ __forceinline__ unsigned cvtpk(float lo, float hi) {
  unsigned r;
  asm("v_cvt_pk_bf16_f32 %0, %1, %2" : "=v"(r) : "v"(lo), "v"(hi));
  return r;
}

// flat f32 -> bf16 cast, 4 elems/thread
__global__ __launch_bounds__(256) void k_cast_x(const float* __restrict__ x,
                                                u16* __restrict__ xb, int n4) {
  int i = blockIdx.x * 256 + threadIdx.x;
  if (i >= n4) return;
  float4 v = reinterpret_cast<const float4*>(x)[i];
  ushort4 o;
  o.x = f2bf(v.x); o.y = f2bf(v.y); o.z = f2bf(v.z); o.w = f2bf(v.w);
  reinterpret_cast<ushort4*>(xb)[i] = o;
}

// Wq/Wk/Wv [H][C][D] f32 -> wt [(m*H+h)*D+d][C] bf16 via LDS tile transpose.
__global__ __launch_bounds__(256) void k_cast_w(const float* __restrict__ Wq,
                                                const float* __restrict__ Wk,
                                                const float* __restrict__ Wv,
                                                u16* __restrict__ wt) {
  __shared__ u16 tile[64][68];
  const int mh = blockIdx.y;
  const int m = mh >> 4, h = mh & 15;
  const float* src = (m == 0 ? Wq : m == 1 ? Wk : Wv) + (size_t)h * Cdim * Dh;
  const int c0 = blockIdx.x * 64;
  const int tid = threadIdx.x;
  const int cc = tid >> 4, d4 = (tid & 15) * 4;
#pragma unroll
  for (int i = 0; i < 4; ++i) {
    int c = i * 16 + cc;
    float4 v = *(const float4*)(src + (size_t)(c0 + c) * Dh + d4);
    tile[d4 + 0][c] = f2bf(v.x);
    tile[d4 + 1][c] = f2bf(v.y);
    tile[d4 + 2][c] = f2bf(v.z);
    tile[d4 + 3][c] = f2bf(v.w);
  }
  __syncthreads();
  const int c4 = (tid & 15) * 4, dd = tid >> 4;
#pragma unroll
  for (int i = 0; i < 4; ++i) {
    int d = i * 16 + dd;
    ushort4 o;
    o.x = tile[d][c4]; o.y = tile[d][c4 + 1];
    o.z = tile[d][c4 + 2]; o.w = tile[d][c4 + 3];
    *(ushort4*)(wt + (size_t)(mh * 64 + d) * Cdim + c0 + c4) = o;
  }
}

// QKV GEMM: 128x128, BK=32, 3-deep counted-vmcnt pipeline, chunk-swizzled LDS.
__global__ __launch_bounds__(256) void k_gemm_qkv(const u16* __restrict__ xb,
                                                  const u16* __restrict__ wt,
                                                  u16* __restrict__ qb,
                                                  u16* __restrict__ kb,
                                                  u16* __restrict__ vtb) {
  __shared__ __align__(16) u16 As[3][4096], Bs[3][4096];
  const int tid = threadIdx.x, lane = tid & 63, wid = tid >> 6;
  const int cl = lane & 15, kg = lane >> 4;
  const int row0 = blockIdx.y * 128, col0 = blockIdx.x * 128;
  const int wrow = (wid >> 1) * 64, wcol = (wid & 1) * 64;
  f32x4 acc[4][4] = {};
  const int csrc = ((lane & 3) ^ ((lane >> 3) & 3)) * 8;
  const u16* a_src = xb + (size_t)(row0 + 32 * wid + (lane >> 2)) * Cdim + csrc;
  const u16* b_src = wt + (size_t)(col0 + 32 * wid + (lane >> 2)) * Cdim + csrc;

  auto stage = [&](int buf, int ke) {
    u16* Ad = &As[buf][1024 * wid];
    u16* Bd = &Bs[buf][1024 * wid];
    GLD16(a_src + ke, Ad);
    GLD16(a_src + 16 * Cdim + ke, Ad + 512);
    GLD16(b_src + ke, Bd);
    GLD16(b_src + 16 * Cdim + ke, Bd + 512);
  };

  const int rdswz = (kg ^ ((cl >> 1) & 3)) * 8;

  stage(0, 0);
  stage(1, 32);
  stage(2, 64);
  for (int kk = 0; kk < 32; ++kk) {
    if (kk < 30)
      asm volatile("s_waitcnt vmcnt(8)" ::: "memory");
    else if (kk == 30)
      asm volatile("s_waitcnt vmcnt(4)" ::: "memory");
    else
      asm volatile("s_waitcnt vmcnt(0)" ::: "memory");
    __builtin_amdgcn_s_barrier();  // all waves: buf[kk%3] ready
    const int cur = kk % 3;
    const u16* ar = &As[cur][(wrow + cl) * 32 + rdswz];
    const u16* br = &Bs[cur][(wcol + cl) * 32 + rdswz];
    bf16x8 af[4], bfr[4];
#pragma unroll
    for (int mi = 0; mi < 4; ++mi) af[mi] = *(const bf16x8*)(ar + mi * 512);
#pragma unroll
    for (int ni = 0; ni < 4; ++ni) bfr[ni] = *(const bf16x8*)(br + ni * 512);
#pragma unroll
    for (int mi = 0; mi < 4; ++mi)
#pragma unroll
      for (int ni = 0; ni < 4; ++ni)
        acc[mi][ni] = MFMA(af[mi], bfr[ni], acc[mi][ni]);
    __builtin_amdgcn_s_barrier();  // all waves done reading buf[kk%3]
    if (kk + 3 < 32) stage(cur, (kk + 3) * 32);
  }
#pragma unroll
  for (int mi = 0; mi < 4; ++mi) {
#pragma unroll
    for (int ni = 0; ni < 4; ++ni) {
      int n = col0 + wcol + ni * 16 + cl;
      int m = n >> 10, h = (n >> 6) & 15, d = n & 63;
#pragma unroll
      for (int j2 = 0; j2 < 4; ++j2) {
        int r = row0 + wrow + mi * 16 + kg * 4 + j2;
        int b = r >> 11, t = r & 2047;
        float av = acc[mi][ni][j2];
        if (m == 0) av *= 0.04508422f;  // 1/sqrt(C) * log2(e)
        u16 v = f2bf(av);
        size_t bh = (size_t)(b * Hn + h);
        if (m == 0)
          qb[(bh * Tsz + t) * Dh + d] = v;
        else if (m == 1)
          kb[(bh * Tsz + t) * Dh + d] = v;
        else
          vtb[(bh * Dh + d) * Tsz + t] = v;
      }
    }
  }
}

// ---- flash attention: 1024 blocks, 1 q-tile/block, LDS-staged dbuf K/V ----
// Grid 1024: xcd = bid&7; s = bid>>3; t = 31-(s>>2) (longest first);
// bh p = xcd + 8*(s&3). All blocks of one (b,h) share an XCD. 4 waves/block,
// wave wid owns q-rows [t*64+wid*16,+16). LDS 40KB -> 4 blocks/CU.
__global__ __launch_bounds__(256, 4) void k_attn(const u16* __restrict__ qb,
                                                 const u16* __restrict__ kb,
                                                 const u16* __restrict__ vtb,
                                                 u16* __restrict__ ob) {
  __shared__ __align__(16) u16 KV[2][8192];   // [buf][ K: 0..4095 | V: 4096..8191 ]
  __shared__ __align__(16) u16 Plds[4][1024]; // per-wave P roundtrip
  const int lane = threadIdx.x & 63, wid = threadIdx.x >> 6;
  const int cl = lane & 15, kg = lane >> 4;
  const int s = blockIdx.x >> 3;
  const int t = 31 - (s >> 2);
  const int p = (blockIdx.x & 7) + 8 * (s & 3);
  const int h = p & 15, b = p >> 4;
  const int qr = t * 64 + wid * 16;
  const size_t bh = (size_t)(b * Hn + h);
  const u16* Qp = qb + bh * Tsz * Dh;
  const u16* Kp = kb + bh * Tsz * Dh;
  const u16* Vp = vtb + bh * Dh * Tsz;

  const u16* pk_src[2];
  const u16* pv_src[2];
#pragma unroll
  for (int c = 0; c < 2; ++c) {
    int lo = c * 4096 + wid * 1024 + lane * 16;
    int r = lo >> 7, cb = lo & 127;
    int cbs = cb ^ ((r & 7) << 4);
    pk_src[c] = Kp + r * Dh + (cbs >> 1);
    pv_src[c] = Vp + (size_t)r * Tsz + (cbs >> 1);
  }

  auto stage = [&](int buf, int kt) {
    GLD16(pk_src[0] + kt * 4096, &KV[buf][(wid * 1024) >> 1]);
    GLD16(pk_src[1] + kt * 4096, &KV[buf][(4096 + wid * 1024) >> 1]);
    GLD16(pv_src[0] + kt * 64, &KV[buf][(8192 + wid * 1024) >> 1]);
    GLD16(pv_src[1] + kt * 64, &KV[buf][(12288 + wid * 1024) >> 1]);
  };

  bf16x8 qa0 = *(const bf16x8*)(Qp + (size_t)(qr + cl) * Dh + kg * 8);
  bf16x8 qa1 = *(const bf16x8*)(Qp + (size_t)(qr + cl) * Dh + 32 + kg * 8);

  f32x4 o[4] = {};
  float m = NEGINF, l = 0.f;

  char* pb = (char*)&Plds[wid][0];
  const int rdoff0 = ((cl << 7) + (kg << 4)) ^ ((cl & 7) << 4);
  const int rdoff1 = ((cl << 7) + 64 + (kg << 4)) ^ ((cl & 7) << 4);
  const int rowoff = wid * 16;
  const int swz0 = (kg * 16) ^ ((cl & 7) << 4);
  const int swz1 = (kg * 16 + 64) ^ ((cl & 7) << 4);

  stage(0, 0);
  __syncthreads();
  int cur = 0;
  for (int kt = 0; kt <= t; ++kt) {
    if (kt < t) stage(cur ^ 1, kt + 1);
    char* kvb = (char*)&KV[cur][0];
    // K frags from LDS
    bf16x8 ka[8];
#pragma unroll
    for (int nt = 0; nt < 4; ++nt) {
      int rbase = (nt * 16 + cl) << 7;
      ka[nt * 2] = *(const bf16x8*)(kvb + rbase + swz0);
      ka[nt * 2 + 1] = *(const bf16x8*)(kvb + rbase + swz1);
    }
    f32x4 sv[4];
    __builtin_amdgcn_s_setprio(1);
#pragma unroll
    for (int nt = 0; nt < 4; ++nt) {
      f32x4 z = {};
      z = MFMA(ka[nt * 2], qa0, z);
      z = MFMA(ka[nt * 2 + 1], qa1, z);
      sv[nt] = z;
    }
    __builtin_amdgcn_s_setprio(0);
    // V frags from LDS
    bf16x8 vf[8];
#pragma unroll
    for (int dt = 0; dt < 4; ++dt) {
      int rbase = 8192 + ((dt * 16 + cl) << 7);
      vf[dt * 2] = *(const bf16x8*)(kvb + rbase + swz0);
      vf[dt * 2 + 1] = *(const bf16x8*)(kvb + rbase + swz1);
    }
    if (kt == t) {  // diag tile mask
#pragma unroll
      for (int nt = 0; nt < 4; ++nt)
#pragma unroll
        for (int j = 0; j < 4; ++j)
          if (nt * 16 + kg * 4 + j > rowoff + cl) sv[nt][j] = NEGINF;
    }
    float tm = fmaxf(fmaxf(fmaxf(sv[0][0], sv[0][1]), fmaxf(sv[0][2], sv[0][3])),
                     fmaxf(fmaxf(sv[1][0], sv[1][1]), fmaxf(sv[1][2], sv[1][3])));
    tm = fmaxf(tm, fmaxf(fmaxf(fmaxf(sv[2][0], sv[2][1]), fmaxf(sv[2][2], sv[2][3])),
                         fmaxf(fmaxf(sv[3][0], sv[3][1]), fmaxf(sv[3][2], sv[3][3]))));
    if (!__all(tm <= m + 8.0f)) {
      tm = fmaxf(tm, __shfl_xor(tm, 16));
      tm = fmaxf(tm, __shfl_xor(tm, 32));
      float mnew = fmaxf(m, tm);
      float corr = EXP2(m - mnew);
      m = mnew;
      l *= corr;
      float c0 = __shfl(corr, kg * 4 + 0);
      float c1 = __shfl(corr, kg * 4 + 1);
      float c2 = __shfl(corr, kg * 4 + 2);
      float c3 = __shfl(corr, kg * 4 + 3);
#pragma unroll
      for (int dt = 0; dt < 4; ++dt) {
        o[dt][0] *= c0; o[dt][1] *= c1; o[dt][2] *= c2; o[dt][3] *= c3;
      }
    }
    float rs = 0.f;
#pragma unroll
    for (int nt = 0; nt < 4; ++nt)
#pragma unroll
      for (int j = 0; j < 4; ++j) {
        float pv = EXP2(sv[nt][j] - m);
        sv[nt][j] = pv;
        rs += pv;
      }
    l += rs;
#pragma unroll
    for (int nt = 0; nt < 4; ++nt) {
      uint2 pk;
      pk.x = cvtpk(sv[nt][0], sv[nt][1]);
      pk.y = cvtpk(sv[nt][2], sv[nt][3]);
      int waddr = ((cl << 7) + (nt << 5) + (kg << 3)) ^ ((cl & 7) << 4);
      *(uint2*)(pb + waddr) = pk;
    }
    bf16x8 pa0 = *(const bf16x8*)(pb + rdoff0);
    bf16x8 pa1 = *(const bf16x8*)(pb + rdoff1);
    __builtin_amdgcn_s_setprio(1);
#pragma unroll
    for (int dt = 0; dt < 4; ++dt) {
      o[dt] = MFMA(pa0, vf[dt * 2], o[dt]);
      o[dt] = MFMA(pa1, vf[dt * 2 + 1], o[dt]);
    }
    __builtin_amdgcn_s_setprio(0);
    __syncthreads();  // drains next-tile gld_lds + protects buffer reuse
    cur ^= 1;
  }

  // epilogue: finish lazy l reduction, broadcast 1/l per O row
  l += __shfl_xor(l, 16);
  l += __shfl_xor(l, 32);
  float i0 = 1.f / __shfl(l, kg * 4 + 0), i1 = 1.f / __shfl(l, kg * 4 + 1);
  float i2 = 1.f / __shfl(l, kg * 4 + 2), i3 = 1.f / __shfl(l, kg * 4 + 3);
  float inv[4] = {i0, i1, i2, i3};
#pragma unroll
  for (int dt = 0; dt < 4; ++dt)
#pragma unroll
    for (int j = 0; j < 4; ++j) {
      int tr = qr + kg * 4 + j;
      ob[(size_t)(b * Tsz + tr) * Cdim + h * Dh + dt * 16 + cl] = f2bf(o[dt][j] * inv[j]);
    }
}

// Out GEMM: 128x64 tile, BK=32, 3-deep counted-vmcnt pipeline.
__global__ __launch_bounds__(256) void k_gemm_out(const u16* __restrict__ ob,
                                                  const u16* __restrict__ wob,
                                                  const float* __restrict__ bo,
                                                  float* __restrict__ out) {
  __shared__ __align__(16) u16 As[3][4096], Bs[3][2048];
  const int tid = threadIdx.x, lane = tid & 63, wid = tid >> 6;
  const int cl = lane & 15, kg = lane >> 4;
  const int row0 = blockIdx.y * 128, col0 = blockIdx.x * 64;
  const int wrow = (wid >> 1) * 64, wcol = (wid & 1) * 32;
  f32x4 acc[4][2] = {};
  const int csrc = ((lane & 3) ^ ((lane >> 3) & 3)) * 8;
  const u16* a_src = ob + (size_t)(row0 + 32 * wid + (lane >> 2)) * Cdim + csrc;
  const u16* b_src = wob + (size_t)(col0 + 16 * wid + (lane >> 2)) * Cdim + csrc;

  auto stage = [&](int buf, int ke) {
    u16* Ad = &As[buf][1024 * wid];
    u16* Bd = &Bs[buf][512 * wid];
    GLD16(a_src + ke, Ad);
    GLD16(a_src + 16 * Cdim + ke, Ad + 512);
    GLD16(b_src + ke, Bd);
  };

  const int rdswz = (kg ^ ((cl >> 1) & 3)) * 8;

  stage(0, 0);
  stage(1, 32);
  stage(2, 64);
  for (int kk = 0; kk < 32; ++kk) {
    if (kk < 30)
      asm volatile("s_waitcnt vmcnt(6)" ::: "memory");
    else if (kk == 30)
      asm volatile("s_waitcnt vmcnt(3)" ::: "memory");
    else
      asm volatile("s_waitcnt vmcnt(0)" ::: "memory");
    __builtin_amdgcn_s_barrier();
    const int cur = kk % 3;
    const u16* ar = &As[cur][(wrow + cl) * 32 + rdswz];
    const u16* br = &Bs[cur][(wcol + cl) * 32 + rdswz];
    bf16x8 af[4], bfr[2];
#pragma unroll
    for (int mi = 0; mi < 4; ++mi) af[mi] = *(const bf16x8*)(ar + mi * 512);
#pragma unroll
    for (int ni = 0; ni < 2; ++ni) bfr[ni] = *(const bf16x8*)(br + ni * 512);
#pragma unroll
    for (int mi = 0; mi < 4; ++mi)
#pragma unroll
      for (int ni = 0; ni < 2; ++ni)
        acc[mi][ni] = MFMA(af[mi], bfr[ni], acc[mi][ni]);
    __builtin_amdgcn_s_barrier();
    if (kk + 3 < 32) stage(cur, (kk + 3) * 32);
  }
#pragma unroll
  for (int mi = 0; mi < 4; ++mi) {
#pragma unroll
    for (int ni = 0; ni < 2; ++ni) {
      int n = col0 + wcol + ni * 16 + cl;
      float bias = bo[n];
#pragma unroll
      for (int j2 = 0; j2 < 4; ++j2) {
        int r = row0 + wrow + mi * 16 + kg * 4 + j2;
        out[(size_t)r * Cdim + n] = acc[mi][ni][j2] + bias;
      }
    }
  }
}

extern "C" void kernel_launch(void* const* d_in, const int* in_sizes, int n_in,
                              void* d_out, int out_size, void* d_ws, size_t ws_size,
                              hipStream_t stream) {
  (void)in_sizes; (void)n_in; (void)out_size; (void)ws_size;
  const float* x = (const float*)d_in[0];
  const float* Wq = (const float*)d_in[1];
  const float* Wk = (const float*)d_in[2];
  const float* Wv = (const float*)d_in[3];
  const float* Wo = (const float*)d_in[4];
  const float* bo = (const float*)d_in[5];
  float* out = (float*)d_out;
  char* ws = (char*)d_ws;
  u16* xb = (u16*)(ws);                  // 8 MiB  x bf16 [4096][1024]
  u16* wt = (u16*)(ws + (8u << 20));     // 6 MiB  Wqkv^T bf16 [3072][1024]
  u16* wob = (u16*)(ws + (14u << 20));   // 2 MiB  Wo bf16 [1024][1024]
  u16* qb = (u16*)(ws + (16u << 20));    // 8 MiB  Q (pre-scaled)
  u16* kb = (u16*)(ws + (24u << 20));    // 8 MiB  K
  u16* vtb = (u16*)(ws + (32u << 20));   // 8 MiB  V^T
  u16* ob = (u16*)(ws + (40u << 20));    // 8 MiB  attn out bf16

  k_cast_x<<<4096, 256, 0, stream>>>(x, xb, Bsz * Tsz * Cdim / 4);
  k_cast_x<<<1024, 256, 0, stream>>>(Wo, wob, Cdim * Cdim / 4);
  k_cast_w<<<dim3(16, 48), 256, 0, stream>>>(Wq, Wk, Wv, wt);
  k_gemm_qkv<<<dim3(24, 32), 256, 0, stream>>>(xb, wt, qb, kb, vtb);
  k_attn<<<1024, 256, 0, stream>>>(qb, kb, vtb, ob);
  k_gemm_out<<<dim3(16, 32), 256, 0, stream>>>(ob, wob, bo, out);
}